// Round 9
// baseline (841.096 us; speedup 1.0000x reference)
//
#include <hip/hip_runtime.h>
#include <math.h>

#define N_TOT 2048
#define NE    1024
#define BATCH 512
#define IN_SZ 512
#define SS    10240   // STATE_SIZE
#define AI_OFF 3072
#define BE_OFF 6144
#define BI_OFF 7168
#define X_OFF  8192
#define NBLK  256     // grid blocks; 1 per CU -> co-residency guaranteed
#define LDS_B_OFF 16384   // byte offset of B tile within one LDS buffer (A = 64*256B)

typedef __attribute__((ext_vector_type(8))) short bf16x8;
typedef __attribute__((ext_vector_type(4))) float f32x4;

// ---------- device helpers ----------

__device__ __forceinline__ float sp_f(float x) {
    return fmaxf(x, 0.f) + log1pf(expf(-fabsf(x)));
}

__device__ __forceinline__ float psig(float x) {
    if (x >= -0.45f) {
        if (x <= 0.45f) return x + 0.5f;
        if (x > 0.55f)  return 1.f;
        float d = x - 0.55f;
        return 1.f - 5.f * d * d;
    }
    if (x < -0.55f) return 0.f;
    float d = x + 0.55f;
    return 5.f * d * d;
}

__device__ __forceinline__ ushort f2bf(float f) {
    unsigned u = __float_as_uint(f);
    unsigned r = (u + 0x7fffu + ((u >> 16) & 1u)) >> 16;
    return (ushort)r;
}

__device__ __forceinline__ void gload16(const void* g, void* l) {
    __builtin_amdgcn_global_load_lds(
        (const __attribute__((address_space(1))) void*)g,
        (__attribute__((address_space(3))) void*)l, 16, 0, 0);
}

// manual grid barrier: sense via monotonically increasing generation.
// bar[0]=cnt, bar[1]=gen, both zeroed by k_params each call.
__device__ __forceinline__ void gbar(unsigned* bar) {
    __threadfence();              // release my writes (agent scope)
    __syncthreads();
    if (threadIdx.x == 0) {
        unsigned* cnt = bar;
        unsigned* gen = bar + 1;
        unsigned g = __hip_atomic_load(gen, __ATOMIC_RELAXED, __HIP_MEMORY_SCOPE_AGENT);
        unsigned a = __hip_atomic_fetch_add(cnt, 1u, __ATOMIC_ACQ_REL, __HIP_MEMORY_SCOPE_AGENT);
        if (a == NBLK - 1) {
            __hip_atomic_store(cnt, 0u, __ATOMIC_RELAXED, __HIP_MEMORY_SCOPE_AGENT);
            __hip_atomic_fetch_add(gen, 1u, __ATOMIC_RELEASE, __HIP_MEMORY_SCOPE_AGENT);
        } else {
            while (__hip_atomic_load(gen, __ATOMIC_ACQUIRE, __HIP_MEMORY_SCOPE_AGENT) == g) {
                __builtin_amdgcn_s_sleep(2);
            }
        }
    }
    __syncthreads();
    __threadfence();              // acquire side: invalidate caches before re-reads
}

// ---------- params + barrier init ----------
// P: 0 g_x | 1..3 g_aE | 4..6 g_aI | 7..9 c_E | 10..12 c_I | 13..15 c0_E
//    16..18 c0_I | 19 kb_rec_E | 20 kb_rel_E | 21 kb_rec_I | 22 kb_rel_I
//    23..25 1/(1+g_aE) | 26..28 1/(1+g_aI) | 29 1/(1+g_x)
__global__ void k_params(const float* ltd, const float* loE, const float* hiE,
                         const float* lcE, const float* c0E,
                         const float* loI, const float* hiI,
                         const float* lcI, const float* c0I,
                         const float* recE, const float* relE,
                         const float* recI, const float* relI,
                         float* __restrict__ P, unsigned* __restrict__ bar) {
    if (threadIdx.x == 0 && blockIdx.x == 0) {
        bar[0] = 0u;
        bar[1] = 0u;
        const float DTf = (float)(0.04 / 6.0);
        float gx = DTf / sp_f(ltd[0]);
        P[0] = gx;
        P[29] = 1.f / (1.f + gx);
        float sElo = sp_f(loE[0]), sEhi = sp_f(hiE[0]);
        float sIlo = sp_f(loI[0]), sIhi = sp_f(hiI[0]);
        for (int j = 0; j < 3; ++j) {
            float t = 0.5f * (float)j;
            float gE = DTf / (sElo + (sEhi - sElo) * t);
            float gI = DTf / (sIlo + (sIhi - sIlo) * t);
            P[1 + j] = gE;  P[23 + j] = 1.f / (1.f + gE);
            P[4 + j] = gI;  P[26 + j] = 1.f / (1.f + gI);
            P[7 + j]  = sp_f(lcE[j]);
            P[10 + j] = sp_f(lcI[j]);
            P[13 + j] = c0E[j];
            P[16 + j] = c0I[j];
        }
        P[19] = DTf / sp_f(recE[0]);
        P[20] = DTf / sp_f(relE[0]);
        P[21] = DTf / sp_f(recI[0]);
        P[22] = DTf / sp_f(relI[0]);
    }
}

// ---------- W_eff (bf16) = softplus(W_raw) * sign(col) * mask ----------
__global__ __launch_bounds__(256) void k_weff(const float* __restrict__ Wr,
                                              const float* __restrict__ mask,
                                              ushort* __restrict__ We) {
    int i = blockIdx.x * 256 + threadIdx.x;   // float4 index; 1M total
    float4 w = ((const float4*)Wr)[i];
    float4 m = ((const float4*)mask)[i];
    int col = (i * 4) & (N_TOT - 1);
    float s = (col < NE) ? 1.f : -1.f;
    ushort4 o;
    o.x = f2bf(sp_f(w.x) * m.x * s);
    o.y = f2bf(sp_f(w.y) * m.y * s);
    o.z = f2bf(sp_f(w.z) * m.z * s);
    o.w = f2bf(sp_f(w.w) * m.w * s);
    ((ushort4*)We)[i] = o;
}

// ---------- fp32 -> bf16 bulk convert ----------
__global__ __launch_bounds__(256) void k_cvt(const float* __restrict__ in,
                                             ushort* __restrict__ out) {
    int i = blockIdx.x * 256 + threadIdx.x;   // float4 index
    float4 v = ((const float4*)in)[i];
    ushort4 o;
    o.x = f2bf(v.x); o.y = f2bf(v.y); o.z = f2bf(v.z); o.w = f2bf(v.w);
    ((ushort4*)out)[i] = o;
}

// ---------- persistent fused SRNN cell (normal launch + manual grid barrier) ----------
// Grid 32(n) x 8(m) = 256 blocks (1/CU). 512 threads = 8 waves (4m x 2n).
// Tile 64x64, BK=128 double-buffered (64KB LDS: per buf A 16KB + B 16KB).
// Thread owns 8 outputs [j 0..1][q 0..3]; state register-resident across
// 6 unfolds; only r_dep (bf16) crosses grid barriers (double-buffered).
__global__ __launch_bounds__(512, 2)
void kfused(const ushort* __restrict__ We,
            const ushort* __restrict__ u_bf,
            const ushort* __restrict__ win_bf,
            const float* __restrict__ a0,
            const float* __restrict__ P,
            const float* __restrict__ state_in,
            float* __restrict__ state_out,
            ushort* __restrict__ rdep0,
            ushort* __restrict__ rdep1,
            unsigned* __restrict__ bar) {
    // per buf: A 64x128 bf16 (16KB) + B 64x128 bf16 (16KB); x2 = 64KB
    __shared__ __align__(16) ushort lds[2][16384];
    const int tid  = threadIdx.x;
    const int lane = tid & 63;
    const int wv   = tid >> 6;        // 0..7
    const int wr   = wv >> 1;         // 0..3 (m)
    const int wc   = wv & 1;          // 0..1 (n)
    const int bn   = blockIdx.x * 64;
    const int bm   = blockIdx.y * 64;

    // ---- staging: 16 chunks (16B) per 256B row; linear LDS dest,
    //      inverse-swizzled global source: lds[row][c] = G[row][c ^ (row&7)]
    const int srow = tid >> 4;                 // 0..31 (also +32)
    const int sch  = tid & 15;                 // LDS chunk slot
    const int sgc  = sch ^ (srow & 7);         // global chunk ((r+32)&7 == r&7)

    // ---- fragment ds_read byte offsets (loop-invariant) ----
    const int kc = lane >> 4, rr = lane & 15;
    const int ar = wr * 16 + rr;
    int aO[4], bO0[4], bO1[4];
    {
        const int br0 = wc * 32 + rr;
        const int br1 = wc * 32 + 16 + rr;
#pragma unroll
        for (int s = 0; s < 4; ++s) {
            aO[s]  = ar * 256 + (((s * 4 + kc) ^ (ar & 7)) << 4);
            bO0[s] = LDS_B_OFF + br0 * 256 + (((s * 4 + kc) ^ (br0 & 7)) << 4);
            bO1[s] = LDS_B_OFF + br1 * 256 + (((s * 4 + kc) ^ (br1 & 7)) << 4);
        }
    }

    auto stage = [&](int buf, const ushort* A, const ushort* Bt, int K, int k0) {
        char* Ld = (char*)&lds[buf][0];
        const ushort* Ap  = A  + (size_t)(bm + srow) * K + k0 + sgc * 8;
        const ushort* Ap2 = A  + (size_t)(bm + srow + 32) * K + k0 + sgc * 8;
        const ushort* Bp  = Bt + (size_t)(bn + srow) * K + k0 + sgc * 8;
        const ushort* Bp2 = Bt + (size_t)(bn + srow + 32) * K + k0 + sgc * 8;
        gload16(Ap,  Ld + tid * 16);
        gload16(Ap2, Ld + tid * 16 + 8192);
        gload16(Bp,  Ld + LDS_B_OFF + tid * 16);
        gload16(Bp2, Ld + LDS_B_OFF + tid * 16 + 8192);
    };
    auto compute = [&](int buf, f32x4* acc) {
        const char* Ld = (const char*)&lds[buf][0];
#pragma unroll
        for (int s = 0; s < 4; ++s) {
            bf16x8 af = *(const bf16x8*)(Ld + aO[s]);
            bf16x8 b0 = *(const bf16x8*)(Ld + bO0[s]);
            bf16x8 b1 = *(const bf16x8*)(Ld + bO1[s]);
            acc[0] = __builtin_amdgcn_mfma_f32_16x16x32_bf16(af, b0, acc[0], 0, 0, 0);
            acc[1] = __builtin_amdgcn_mfma_f32_16x16x32_bf16(af, b1, acc[1], 0, 0, 0);
        }
    };
    auto gemmK = [&](const ushort* A, const ushort* Bt, int K, f32x4* acc) {
        const int nkt = K >> 7;
        stage(0, A, Bt, K, 0);
        __syncthreads();
        for (int kt = 0; kt < nkt; ++kt) {
            int cur = kt & 1;
            if (kt + 1 < nkt) stage(cur ^ 1, A, Bt, K, (kt + 1) << 7);
            compute(cur, acc);
            __syncthreads();
        }
    };

    // ---- per-thread output coords & hoisted params ----
    const float gx = P[0], inv1gx = P[29];
    const int mbase = bm + wr * 16 + (lane >> 4) * 4;
    int nj[2], aofs[2], bofs[2];
    float ga[2][3], iga[2][3], c0v[2][3], ccv[2][3], kbrecv[2], kbrelv[2];
#pragma unroll
    for (int j = 0; j < 2; ++j) {
        int n = bn + wc * 32 + j * 16 + (lane & 15);
        nj[j] = n;
        bool isE = n < NE;
        int na = isE ? n : n - NE;
#pragma unroll
        for (int c = 0; c < 3; ++c) {
            ga[j][c]  = P[(isE ? 1 : 4) + c];
            iga[j][c] = P[(isE ? 23 : 26) + c];
            c0v[j][c] = P[(isE ? 13 : 16) + c];
            ccv[j][c] = P[(isE ? 7 : 10) + c];
        }
        kbrecv[j] = isE ? P[19] : P[21];
        kbrelv[j] = isE ? P[20] : P[22];
        aofs[j] = (isE ? 0 : AI_OFF) + 3 * na;
        bofs[j] = isE ? (BE_OFF + n) : (BI_OFF + na);
    }

    // ---- I_ext = u @ W_in^T + a_0 (K=512), in registers ----
    f32x4 acc[2];
    acc[0] = f32x4{0.f, 0.f, 0.f, 0.f};
    acc[1] = f32x4{0.f, 0.f, 0.f, 0.f};
    gemmK(u_bf, win_bf, IN_SZ, acc);

    float iext[2][4], xs[2][4], as[2][4][3], bs[2][4], rs[2][4];
#pragma unroll
    for (int j = 0; j < 2; ++j) {
        float a0v = a0[nj[j]];
#pragma unroll
        for (int q = 0; q < 4; ++q) iext[j][q] = acc[j][q] + a0v;
    }

    // ---- load state, compute r0, write rdep0 ----
#pragma unroll
    for (int j = 0; j < 2; ++j) {
#pragma unroll
        for (int q = 0; q < 4; ++q) {
            int m = mbase + q;
            const float* row = state_in + (size_t)m * SS;
            float xv  = row[X_OFF + nj[j]];
            float av0 = row[aofs[j] + 0];
            float av1 = row[aofs[j] + 1];
            float av2 = row[aofs[j] + 2];
            float bv  = row[bofs[j]];
            xs[j][q] = xv;
            as[j][q][0] = av0; as[j][q][1] = av1; as[j][q][2] = av2;
            bs[j][q] = bv;
            float xeff = xv - (av0 * ccv[j][0] + av1 * ccv[j][1] + av2 * ccv[j][2]);
            float rv = psig(xeff);
            rs[j][q] = rv;
            rdep0[(size_t)m * N_TOT + nj[j]] = f2bf(bv * rv);
        }
    }
    gbar(bar);

    // ---- 6 unfolds ----
    ushort* rin  = rdep0;
    ushort* rout = rdep1;
    for (int t = 0; t < 6; ++t) {
        acc[0] = f32x4{0.f, 0.f, 0.f, 0.f};
        acc[1] = f32x4{0.f, 0.f, 0.f, 0.f};
        gemmK(rin, We, N_TOT, acc);
#pragma unroll
        for (int j = 0; j < 2; ++j) {
#pragma unroll
            for (int q = 0; q < 4; ++q) {
                float Isyn = acc[j][q] + iext[j][q];
                float xn = (xs[j][q] + gx * Isyn) * inv1gx;
                xs[j][q] = xn;
                float rv = rs[j][q];
                float an0 = (as[j][q][0] + ga[j][0] * (rv + c0v[j][0])) * iga[j][0];
                float an1 = (as[j][q][1] + ga[j][1] * (rv + c0v[j][1])) * iga[j][1];
                float an2 = (as[j][q][2] + ga[j][2] * (rv + c0v[j][2])) * iga[j][2];
                as[j][q][0] = an0; as[j][q][1] = an1; as[j][q][2] = an2;
                float bnv = (bs[j][q] + kbrecv[j]) /
                            (1.f + kbrecv[j] + kbrelv[j] * rv);
                bs[j][q] = bnv;
                if (t < 5) {
                    float xeff = xn - (an0 * ccv[j][0] + an1 * ccv[j][1] + an2 * ccv[j][2]);
                    float rn = psig(xeff);
                    rs[j][q] = rn;
                    rout[(size_t)(mbase + q) * N_TOT + nj[j]] = f2bf(bnv * rn);
                }
            }
        }
        if (t < 5) {
            gbar(bar);
            ushort* tmp = rin; rin = rout; rout = tmp;
        }
    }

    // ---- write final state ----
#pragma unroll
    for (int j = 0; j < 2; ++j) {
#pragma unroll
        for (int q = 0; q < 4; ++q) {
            float* row = state_out + (size_t)(mbase + q) * SS;
            row[X_OFF + nj[j]] = xs[j][q];
            row[aofs[j] + 0] = as[j][q][0];
            row[aofs[j] + 1] = as[j][q][1];
            row[aofs[j] + 2] = as[j][q][2];
            row[bofs[j]] = bs[j][q];
        }
    }
}

// ---------- launch ----------
extern "C" void kernel_launch(void* const* d_in, const int* in_sizes, int n_in,
                              void* d_out, int out_size, void* d_ws, size_t ws_size,
                              hipStream_t stream) {
    const float* W_raw = (const float*)d_in[0];
    const float* W_in  = (const float*)d_in[1];
    const float* mask  = (const float*)d_in[2];
    const float* a_0   = (const float*)d_in[3];
    const float* ltd   = (const float*)d_in[4];
    const float* loE   = (const float*)d_in[5];
    const float* hiE   = (const float*)d_in[6];
    const float* lcE   = (const float*)d_in[7];
    const float* c0E   = (const float*)d_in[8];
    const float* loI   = (const float*)d_in[9];
    const float* hiI   = (const float*)d_in[10];
    const float* lcI   = (const float*)d_in[11];
    const float* c0I   = (const float*)d_in[12];
    const float* recE  = (const float*)d_in[13];
    const float* relE  = (const float*)d_in[14];
    const float* recI  = (const float*)d_in[15];
    const float* relI  = (const float*)d_in[16];
    const float* u     = (const float*)d_in[17];
    const float* state = (const float*)d_in[18];
    float* out = (float*)d_out;
    char* wsb = (char*)d_ws;

    ushort*   We     = (ushort*)(wsb);                 // 8 MB
    ushort*   rdep0  = (ushort*)(wsb + (8u << 20));    // 2 MB
    ushort*   rdep1  = (ushort*)(wsb + (10u << 20));   // 2 MB
    ushort*   u_bf   = (ushort*)(wsb + (12u << 20));   // 0.5 MB
    ushort*   win_bf = (ushort*)(wsb + (13u << 20));   // 2 MB
    unsigned* bar    = (unsigned*)(wsb + (15u << 20)); // 8 B
    float*    P      = (float*)(wsb + (15u << 20) + 256);

    k_params<<<1, 64, 0, stream>>>(ltd, loE, hiE, lcE, c0E, loI, hiI, lcI, c0I,
                                   recE, relE, recI, relI, P, bar);

    k_weff<<<(N_TOT * N_TOT / 4) / 256, 256, 0, stream>>>(W_raw, mask, We);
    k_cvt<<<(BATCH * IN_SZ / 4) / 256, 256, 0, stream>>>(u, u_bf);
    k_cvt<<<(N_TOT * IN_SZ / 4) / 256, 256, 0, stream>>>(W_in, win_bf);

    kfused<<<dim3(32, 8), 512, 0, stream>>>(We, u_bf, win_bf, a_0, P,
                                            state, out, rdep0, rdep1, bar);
}

// Round 14
// 770.848 us; speedup vs baseline: 1.0911x; 1.0911x over previous
//
#include <hip/hip_runtime.h>
#include <math.h>

#define N_TOT 2048
#define NE    1024
#define BATCH 512
#define IN_SZ 512
#define SS    10240   // STATE_SIZE
#define AI_OFF 3072
#define BE_OFF 6144
#define BI_OFF 7168
#define X_OFF  8192

typedef __attribute__((ext_vector_type(8))) short bf16x8;
typedef __attribute__((ext_vector_type(4))) float f32x4;

// ---------- device helpers ----------

__device__ __forceinline__ float sp_f(float x) {
    return fmaxf(x, 0.f) + log1pf(expf(-fabsf(x)));
}

__device__ __forceinline__ float psig(float x) {
    if (x >= -0.45f) {
        if (x <= 0.45f) return x + 0.5f;
        if (x > 0.55f)  return 1.f;
        float d = x - 0.55f;
        return 1.f - 5.f * d * d;
    }
    if (x < -0.55f) return 0.f;
    float d = x + 0.55f;
    return 5.f * d * d;
}

__device__ __forceinline__ ushort f2bf(float f) {
    unsigned u = __float_as_uint(f);
    unsigned r = (u + 0x7fffu + ((u >> 16) & 1u)) >> 16;
    return (ushort)r;
}

__device__ __forceinline__ void gload16(const void* g, void* l) {
    __builtin_amdgcn_global_load_lds(
        (const __attribute__((address_space(1))) void*)g,
        (__attribute__((address_space(3))) void*)l, 16, 0, 0);
}

// ---------- params + flag init ----------
// P: 0 g_x | 1..3 g_aE | 4..6 g_aI | 7..9 c_E | 10..12 c_I | 13..15 c0_E
//    16..18 c0_I | 19 kb_rec_E | 20 kb_rel_E | 21 kb_rec_I | 22 kb_rel_I
//    23..25 1/(1+g_aE) | 26..28 1/(1+g_aI) | 29 1/(1+g_x)
__global__ void k_params(const float* ltd, const float* loE, const float* hiE,
                         const float* lcE, const float* c0E,
                         const float* loI, const float* hiI,
                         const float* lcI, const float* c0I,
                         const float* recE, const float* relE,
                         const float* recI, const float* relI,
                         float* __restrict__ P, unsigned* __restrict__ flags) {
    // zero the 512 producer flags (ws is re-poisoned each call)
    for (int j = threadIdx.x; j < 512; j += 64) flags[j] = 0u;
    if (threadIdx.x == 0 && blockIdx.x == 0) {
        const float DTf = (float)(0.04 / 6.0);
        float gx = DTf / sp_f(ltd[0]);
        P[0] = gx;
        P[29] = 1.f / (1.f + gx);
        float sElo = sp_f(loE[0]), sEhi = sp_f(hiE[0]);
        float sIlo = sp_f(loI[0]), sIhi = sp_f(hiI[0]);
        for (int j = 0; j < 3; ++j) {
            float t = 0.5f * (float)j;
            float gE = DTf / (sElo + (sEhi - sElo) * t);
            float gI = DTf / (sIlo + (sIhi - sIlo) * t);
            P[1 + j] = gE;  P[23 + j] = 1.f / (1.f + gE);
            P[4 + j] = gI;  P[26 + j] = 1.f / (1.f + gI);
            P[7 + j]  = sp_f(lcE[j]);
            P[10 + j] = sp_f(lcI[j]);
            P[13 + j] = c0E[j];
            P[16 + j] = c0I[j];
        }
        P[19] = DTf / sp_f(recE[0]);
        P[20] = DTf / sp_f(relE[0]);
        P[21] = DTf / sp_f(recI[0]);
        P[22] = DTf / sp_f(relI[0]);
    }
}

// ---------- W_eff (bf16) = softplus(W_raw) * sign(col) * mask ----------
__global__ __launch_bounds__(256) void k_weff(const float* __restrict__ Wr,
                                              const float* __restrict__ mask,
                                              ushort* __restrict__ We) {
    int i = blockIdx.x * 256 + threadIdx.x;   // float4 index; 1M total
    float4 w = ((const float4*)Wr)[i];
    float4 m = ((const float4*)mask)[i];
    int col = (i * 4) & (N_TOT - 1);
    float s = (col < NE) ? 1.f : -1.f;
    ushort4 o;
    o.x = f2bf(sp_f(w.x) * m.x * s);
    o.y = f2bf(sp_f(w.y) * m.y * s);
    o.z = f2bf(sp_f(w.z) * m.z * s);
    o.w = f2bf(sp_f(w.w) * m.w * s);
    ((ushort4*)We)[i] = o;
}

// ---------- fp32 -> bf16 bulk convert ----------
__global__ __launch_bounds__(256) void k_cvt(const float* __restrict__ in,
                                             ushort* __restrict__ out) {
    int i = blockIdx.x * 256 + threadIdx.x;   // float4 index
    float4 v = ((const float4*)in)[i];
    ushort4 o;
    o.x = f2bf(v.x); o.y = f2bf(v.y); o.z = f2bf(v.z); o.w = f2bf(v.w);
    ((ushort4*)out)[i] = o;
}

// ---------- persistent fused SRNN cell (flag-sync, 2 blocks/CU) ----------
// Grid 32(n) x 16(m) = 512 blocks (2/CU; LDS 24KB -> 6/CU capacity, all
// resident). 256 threads = 4 waves (2m x 2n); tile BM=32 x BN=64, BK=64
// double-buffered. Thread owns 8 outputs [j 0..1][q 0..3]; state lives in
// registers across 6 unfolds; only r_dep (bf16) crosses unfolds.
// Sync: flags[mtile][ntile] = generation; consumer (bm,*) waits for its
// row's 32 producer flags (RELAXED poll + __threadfence on success).
__global__ __launch_bounds__(256, 2)
void kfused(const ushort* __restrict__ We,
            const ushort* __restrict__ u_bf,
            const ushort* __restrict__ win_bf,
            const float* __restrict__ a0,
            const float* __restrict__ P,
            const float* __restrict__ state_in,
            float* __restrict__ state_out,
            ushort* __restrict__ rdep0,
            ushort* __restrict__ rdep1,
            unsigned* __restrict__ flags) {
    // per buf: A 32x64 bf16 (4KB) + B 64x64 bf16 (8KB) = 12KB; x2 = 24KB
    __shared__ __align__(16) ushort lds[2][6144];
    const int tid  = threadIdx.x;
    const int lane = tid & 63;
    const int wv   = tid >> 6;        // 0..3
    const int wr   = wv >> 1;         // 0..1 (m)
    const int wc   = wv & 1;          // 0..1 (n)
    const int bn   = blockIdx.x * 64;
    const int bm   = blockIdx.y * 32;
    unsigned* rowflags = flags + blockIdx.y * 32;

    // ---- staging: 8 chunks (16B) per 128B row; linear LDS dest,
    //      inverse-swizzled global source: lds[row][c] = G[row][c ^ (row&7)]
    const int arow = tid >> 3;                 // 0..31
    const int sgc  = (tid & 7) ^ (arow & 7);   // global chunk

    // ---- fragment ds_read byte offsets (loop-invariant; swizzled) ----
    const int kc = lane >> 4, rr = lane & 15;
    const int ar = wr * 16 + rr;
    int aO[2], bO0[2], bO1[2];
    {
        const int br0 = wc * 32 + rr;
        const int br1 = wc * 32 + 16 + rr;
#pragma unroll
        for (int s = 0; s < 2; ++s) {
            aO[s]  = ar * 128 + (((s * 4 + kc) ^ (ar & 7)) << 4);
            bO0[s] = 4096 + br0 * 128 + (((s * 4 + kc) ^ (br0 & 7)) << 4);
            bO1[s] = 4096 + br1 * 128 + (((s * 4 + kc) ^ (br1 & 7)) << 4);
        }
    }

    auto stage = [&](int buf, const ushort* A, const ushort* Bt, int K, int k0) {
        char* Ld = (char*)&lds[buf][0];
        gload16(A + (size_t)(bm + arow) * K + k0 + sgc * 8, Ld + tid * 16);
        gload16(Bt + (size_t)(bn + arow) * K + k0 + sgc * 8, Ld + 4096 + tid * 16);
        gload16(Bt + (size_t)(bn + arow + 32) * K + k0 + sgc * 8, Ld + 8192 + tid * 16);
    };
    auto compute = [&](int buf, f32x4* acc) {
        const char* Ld = (const char*)&lds[buf][0];
#pragma unroll
        for (int s = 0; s < 2; ++s) {
            bf16x8 af = *(const bf16x8*)(Ld + aO[s]);
            bf16x8 b0 = *(const bf16x8*)(Ld + bO0[s]);
            bf16x8 b1 = *(const bf16x8*)(Ld + bO1[s]);
            acc[0] = __builtin_amdgcn_mfma_f32_16x16x32_bf16(af, b0, acc[0], 0, 0, 0);
            acc[1] = __builtin_amdgcn_mfma_f32_16x16x32_bf16(af, b1, acc[1], 0, 0, 0);
        }
    };
    auto gemmK = [&](const ushort* A, const ushort* Bt, int K, f32x4* acc) {
        const int nkt = K >> 6;
        stage(0, A, Bt, K, 0);
        __syncthreads();
        for (int kt = 0; kt < nkt; ++kt) {
            int cur = kt & 1;
            if (kt + 1 < nkt) stage(cur ^ 1, A, Bt, K, (kt + 1) << 6);
            compute(cur, acc);
            __syncthreads();
        }
    };

    // consumer: wait until all 32 producers of this m-row reach generation g
    auto wait_row = [&](unsigned g) {
        if (wv == 0) {
            const unsigned* f = rowflags + (lane & 31);
            while (__hip_atomic_load(f, __ATOMIC_RELAXED,
                                     __HIP_MEMORY_SCOPE_AGENT) < g) {
                __builtin_amdgcn_s_sleep(4);
            }
        }
        __syncthreads();
        __threadfence();   // acquire: invalidate caches before reading rin
    };
    // producer: publish generation g for this (m-row, n-col) block
    auto signal_row = [&](unsigned g) {
        __syncthreads();   // all threads' rdep writes issued & drained
        __threadfence();   // release: flush rdep writes agent-wide
        if (tid == 0)
            __hip_atomic_store(rowflags + blockIdx.x, g, __ATOMIC_RELAXED,
                               __HIP_MEMORY_SCOPE_AGENT);
    };

    // ---- per-thread output coords & hoisted params ----
    const float gx = P[0], inv1gx = P[29];
    const int mbase = bm + wr * 16 + (lane >> 4) * 4;
    int nj[2], aofs[2], bofs[2];
    float ga[2][3], iga[2][3], c0v[2][3], ccv[2][3], kbrecv[2], kbrelv[2];
#pragma unroll
    for (int j = 0; j < 2; ++j) {
        int n = bn + wc * 32 + j * 16 + (lane & 15);
        nj[j] = n;
        bool isE = n < NE;
        int na = isE ? n : n - NE;
#pragma unroll
        for (int c = 0; c < 3; ++c) {
            ga[j][c]  = P[(isE ? 1 : 4) + c];
            iga[j][c] = P[(isE ? 23 : 26) + c];
            c0v[j][c] = P[(isE ? 13 : 16) + c];
            ccv[j][c] = P[(isE ? 7 : 10) + c];
        }
        kbrecv[j] = isE ? P[19] : P[21];
        kbrelv[j] = isE ? P[20] : P[22];
        aofs[j] = (isE ? 0 : AI_OFF) + 3 * na;
        bofs[j] = isE ? (BE_OFF + n) : (BI_OFF + na);
    }

    // ---- I_ext = u @ W_in^T + a_0 (K=512), in registers ----
    f32x4 acc[2];
    acc[0] = f32x4{0.f, 0.f, 0.f, 0.f};
    acc[1] = f32x4{0.f, 0.f, 0.f, 0.f};
    gemmK(u_bf, win_bf, IN_SZ, acc);

    float iext[2][4], xs[2][4], as[2][4][3], bs[2][4], rs[2][4];
#pragma unroll
    for (int j = 0; j < 2; ++j) {
        float a0v = a0[nj[j]];
#pragma unroll
        for (int q = 0; q < 4; ++q) iext[j][q] = acc[j][q] + a0v;
    }

    // ---- load state, compute r0, write rdep0 (generation 1) ----
#pragma unroll
    for (int j = 0; j < 2; ++j) {
#pragma unroll
        for (int q = 0; q < 4; ++q) {
            int m = mbase + q;
            const float* row = state_in + (size_t)m * SS;
            float xv  = row[X_OFF + nj[j]];
            float av0 = row[aofs[j] + 0];
            float av1 = row[aofs[j] + 1];
            float av2 = row[aofs[j] + 2];
            float bv  = row[bofs[j]];
            xs[j][q] = xv;
            as[j][q][0] = av0; as[j][q][1] = av1; as[j][q][2] = av2;
            bs[j][q] = bv;
            float xeff = xv - (av0 * ccv[j][0] + av1 * ccv[j][1] + av2 * ccv[j][2]);
            float rv = psig(xeff);
            rs[j][q] = rv;
            rdep0[(size_t)m * N_TOT + nj[j]] = f2bf(bv * rv);
        }
    }
    signal_row(1u);

    // ---- 6 unfolds ----
    ushort* rin  = rdep0;
    ushort* rout = rdep1;
    for (int t = 0; t < 6; ++t) {
        wait_row((unsigned)(t + 1));   // rin (gen t+1) ready for this row
        acc[0] = f32x4{0.f, 0.f, 0.f, 0.f};
        acc[1] = f32x4{0.f, 0.f, 0.f, 0.f};
        gemmK(rin, We, N_TOT, acc);
#pragma unroll
        for (int j = 0; j < 2; ++j) {
#pragma unroll
            for (int q = 0; q < 4; ++q) {
                float Isyn = acc[j][q] + iext[j][q];
                float xn = (xs[j][q] + gx * Isyn) * inv1gx;
                xs[j][q] = xn;
                float rv = rs[j][q];
                float an0 = (as[j][q][0] + ga[j][0] * (rv + c0v[j][0])) * iga[j][0];
                float an1 = (as[j][q][1] + ga[j][1] * (rv + c0v[j][1])) * iga[j][1];
                float an2 = (as[j][q][2] + ga[j][2] * (rv + c0v[j][2])) * iga[j][2];
                as[j][q][0] = an0; as[j][q][1] = an1; as[j][q][2] = an2;
                float bnv = (bs[j][q] + kbrecv[j]) /
                            (1.f + kbrecv[j] + kbrelv[j] * rv);
                bs[j][q] = bnv;
                if (t < 5) {
                    float xeff = xn - (an0 * ccv[j][0] + an1 * ccv[j][1] + an2 * ccv[j][2]);
                    float rn = psig(xeff);
                    rs[j][q] = rn;
                    rout[(size_t)(mbase + q) * N_TOT + nj[j]] = f2bf(bnv * rn);
                }
            }
        }
        if (t < 5) {
            signal_row((unsigned)(t + 2));
            ushort* tmp = rin; rin = rout; rout = tmp;
        }
    }

    // ---- write final state ----
#pragma unroll
    for (int j = 0; j < 2; ++j) {
#pragma unroll
        for (int q = 0; q < 4; ++q) {
            float* row = state_out + (size_t)(mbase + q) * SS;
            row[X_OFF + nj[j]] = xs[j][q];
            row[aofs[j] + 0] = as[j][q][0];
            row[aofs[j] + 1] = as[j][q][1];
            row[aofs[j] + 2] = as[j][q][2];
            row[bofs[j]] = bs[j][q];
        }
    }
}

// ---------- launch ----------
extern "C" void kernel_launch(void* const* d_in, const int* in_sizes, int n_in,
                              void* d_out, int out_size, void* d_ws, size_t ws_size,
                              hipStream_t stream) {
    const float* W_raw = (const float*)d_in[0];
    const float* W_in  = (const float*)d_in[1];
    const float* mask  = (const float*)d_in[2];
    const float* a_0   = (const float*)d_in[3];
    const float* ltd   = (const float*)d_in[4];
    const float* loE   = (const float*)d_in[5];
    const float* hiE   = (const float*)d_in[6];
    const float* lcE   = (const float*)d_in[7];
    const float* c0E   = (const float*)d_in[8];
    const float* loI   = (const float*)d_in[9];
    const float* hiI   = (const float*)d_in[10];
    const float* lcI   = (const float*)d_in[11];
    const float* c0I   = (const float*)d_in[12];
    const float* recE  = (const float*)d_in[13];
    const float* relE  = (const float*)d_in[14];
    const float* recI  = (const float*)d_in[15];
    const float* relI  = (const float*)d_in[16];
    const float* u     = (const float*)d_in[17];
    const float* state = (const float*)d_in[18];
    float* out = (float*)d_out;
    char* wsb = (char*)d_ws;

    ushort*   We     = (ushort*)(wsb);                 // 8 MB
    ushort*   rdep0  = (ushort*)(wsb + (8u << 20));    // 2 MB
    ushort*   rdep1  = (ushort*)(wsb + (10u << 20));   // 2 MB
    ushort*   u_bf   = (ushort*)(wsb + (12u << 20));   // 0.5 MB
    ushort*   win_bf = (ushort*)(wsb + (13u << 20));   // 2 MB
    unsigned* flags  = (unsigned*)(wsb + (15u << 20)); // 2 KB
    float*    P      = (float*)(wsb + (15u << 20) + 4096);

    k_params<<<1, 64, 0, stream>>>(ltd, loE, hiE, lcE, c0E, loI, hiI, lcI, c0I,
                                   recE, relE, recI, relI, P, flags);

    k_weff<<<(N_TOT * N_TOT / 4) / 256, 256, 0, stream>>>(W_raw, mask, We);
    k_cvt<<<(BATCH * IN_SZ / 4) / 256, 256, 0, stream>>>(u, u_bf);
    k_cvt<<<(N_TOT * IN_SZ / 4) / 256, 256, 0, stream>>>(W_in, win_bf);

    kfused<<<dim3(32, 16), 256, 0, stream>>>(We, u_bf, win_bf, a_0, P,
                                             state, out, rdep0, rdep1, flags);
}